// Round 9
// baseline (1686.215 us; speedup 1.0000x reference)
//
#include <hip/hip_runtime.h>
#include <math.h>

#define NIMG 8
#define CIN 8
#define Hh 136
#define Ww 200
#define HW (Hh * Ww)
#define OH 272
#define OW 400
#define NINST 512
#define NPAR 169
#define TROWS 34
#define NTILES 8
#define LROWS 19

// LDS weight block layout (word offsets)
#define WOFF_WF 0     /* [o*8+c], 64 */
#define WOFF_AC 64    /* [o*4 + {A0,Ax,Ay,pad}], 32 */
#define WOFF_W1 96    /* [o*8+c], 64 */
#define WOFF_B1 160   /* [o], 8 */
#define WOFF_W2 168   /* [o], 8 */
#define WOFF_B2 176

// One block per (tile, instance). Weights live in LDS and are re-read as
// float4 *broadcasts* each quad-iteration (wave-uniform addr -> no bank
// conflicts, ~12cyc). R2-R8 lesson: the RA never keeps >~100 values live,
// so make the reload source LDS instead of HBM/scratch and stop pinning.
__global__ __launch_bounds__(256, 4) void dmh_fused3(
    const float* __restrict__ feats,
    const float* __restrict__ pars,
    const float* __restrict__ iloc,
    const float* __restrict__ gt,
    const int* __restrict__ iminds,
    const int* __restrict__ lvls,
    float* __restrict__ part)
{
    __shared__ __align__(16) float swt[192];           // packed weights
    __shared__ __align__(16) float slog[LROWS * Ww];   // 15.2 KB logits
    __shared__ float sred[12];

    const int n    = blockIdx.y;
    const int tile = blockIdx.x;
    const int tid  = threadIdx.x;

    const int   im = iminds[n];
    const float* pp = pars + n * NPAR;

    // ---- stage weights into LDS (A-coeffs precomputed) ----
    if (tid < 8) {
        const int o = tid;
        const float ix = iloc[2 * n + 0];
        const float iy = iloc[2 * n + 1];
        const float invsoi = 1.0f / (float)(64 << lvls[n]);
        const float wx0 = pp[o * 10 + 0];
        const float wy0 = pp[o * 10 + 1];
        swt[WOFF_AC + o * 4 + 0] = pp[152 + o] + (wx0 * (ix - 4.0f) + wy0 * (iy - 4.0f)) * invsoi;
        swt[WOFF_AC + o * 4 + 1] = -8.0f * invsoi * wx0;   // Ax
        swt[WOFF_AC + o * 4 + 2] = -8.0f * invsoi * wy0;   // Ay
        swt[WOFF_AC + o * 4 + 3] = 0.0f;
#pragma unroll
        for (int c = 0; c < 8; c++) swt[WOFF_WF + o * 8 + c] = pp[o * 10 + 2 + c];
    } else if (tid < 16) {
        const int o = tid - 8;
#pragma unroll
        for (int c = 0; c < 8; c++) swt[WOFF_W1 + o * 8 + c] = pp[80 + o * 8 + c];
    } else if (tid == 16) {
#pragma unroll
        for (int o = 0; o < 8; o++) swt[WOFF_B1 + o] = pp[160 + o];
    } else if (tid == 17) {
#pragma unroll
        for (int o = 0; o < 8; o++) swt[WOFF_W2 + o] = pp[144 + o];
        swt[WOFF_B2] = pp[168];
    }

    const float sy = 135.0f / 271.0f;
    const float sx = 199.0f / 399.0f;

    const int oy0 = tile * TROWS;
    const int ly0 = (int)((float)oy0 * sy);
    int lyL = (int)((float)(oy0 + TROWS - 1) * sy) + 1;
    if (lyL > Hh - 1) lyL = Hh - 1;
    const int lycnt = lyL - ly0 + 1;
    const int nq    = lycnt * (Ww / 4);      // quads, <= 950

    const float* fb0 = feats + (size_t)im * (CIN * HW) + ly0 * Ww;

    __syncthreads();

    // ================= MLP: each thread computes a 4-px quad =================
    for (int q = tid; q < nq; q += 256) {
        const int yy = q / 50;
        const int xq = (q - yy * 50) * 4;
        const float yf = (float)(ly0 + yy);
        const float* fb = fb0 + yy * Ww + xq;
        float f[8][4];
#pragma unroll
        for (int c = 0; c < 8; c++) {
            const float4 t = *reinterpret_cast<const float4*>(fb + c * HW);
            f[c][0] = t.x; f[c][1] = t.y; f[c][2] = t.z; f[c][3] = t.w;
        }

        // layer 1: h[o][p], weights streamed from LDS per o
        float h[8][4];
#pragma unroll
        for (int o = 0; o < 8; o++) {
            const float4 wA  = *reinterpret_cast<const float4*>(&swt[WOFF_AC + o * 4]);
            const float4 wf0 = *reinterpret_cast<const float4*>(&swt[WOFF_WF + o * 8]);
            const float4 wf1 = *reinterpret_cast<const float4*>(&swt[WOFF_WF + o * 8 + 4]);
            const float py = wA.x + wA.z * yf;
#pragma unroll
            for (int p = 0; p < 4; p++) {
                float a = py + wA.y * (float)(xq + p);
                a += wf0.x * f[0][p]; a += wf0.y * f[1][p];
                a += wf0.z * f[2][p]; a += wf0.w * f[3][p];
                a += wf1.x * f[4][p]; a += wf1.y * f[5][p];
                a += wf1.z * f[6][p]; a += wf1.w * f[7][p];
                h[o][p] = fmaxf(a, 0.0f);
            }
        }

        // layers 2+3: lg[p] accumulated on the fly
        const float b2v = swt[WOFF_B2];
        float lg[4] = { b2v, b2v, b2v, b2v };
#pragma unroll
        for (int o = 0; o < 8; o++) {
            const float4 w10 = *reinterpret_cast<const float4*>(&swt[WOFF_W1 + o * 8]);
            const float4 w11 = *reinterpret_cast<const float4*>(&swt[WOFF_W1 + o * 8 + 4]);
            const float b1o = swt[WOFF_B1 + o];
            const float w2o = swt[WOFF_W2 + o];
#pragma unroll
            for (int p = 0; p < 4; p++) {
                float a = b1o;
                a += w10.x * h[0][p]; a += w10.y * h[1][p];
                a += w10.z * h[2][p]; a += w10.w * h[3][p];
                a += w11.x * h[4][p]; a += w11.y * h[5][p];
                a += w11.z * h[6][p]; a += w11.w * h[7][p];
                lg[p] += w2o * fmaxf(a, 0.0f);
            }
        }
        *reinterpret_cast<float4*>(&slog[q * 4]) =
            make_float4(lg[0], lg[1], lg[2], lg[3]);
    }
    __syncthreads();

    // ================= dice: bilinear + sigmoid + partial sums =================
    float aI = 0.0f, aS = 0.0f, aT = 0.0f;
    const float* gtn = gt + (size_t)n * (OH * OW) + (size_t)oy0 * OW;
    for (int g4 = tid; g4 < TROWS * (OW / 4); g4 += 256) {
        const int ry = g4 / 100;
        const int gx = (g4 - ry * 100) * 4;
        const int oy = oy0 + ry;
        const float ysf = (float)oy * sy;
        const int y0 = (int)ysf;
        const float wy = ysf - (float)y0;
        const int y1 = (y0 + 1 > Hh - 1) ? (Hh - 1) : (y0 + 1);
        int r0i = y0 - ly0, r1i = y1 - ly0;
        r0i = r0i < 0 ? 0 : (r0i > lycnt - 1 ? lycnt - 1 : r0i);
        r1i = r1i < 0 ? 0 : (r1i > lycnt - 1 ? lycnt - 1 : r1i);
        const float* s0 = &slog[r0i * Ww];
        const float* s1 = &slog[r1i * Ww];

        const float4 t4 = *reinterpret_cast<const float4*>(gtn + ry * OW + gx);
        const float tv[4] = { t4.x, t4.y, t4.z, t4.w };
#pragma unroll
        for (int p = 0; p < 4; p++) {
            const int ox = gx + p;
            const float xsf = (float)ox * sx;
            const int x0 = (int)xsf;
            const float wx = xsf - (float)x0;
            const int x1 = (x0 + 1 > Ww - 1) ? (Ww - 1) : (x0 + 1);
            const float v00 = s0[x0];
            const float v01 = s0[x1];
            const float v10 = s1[x0];
            const float v11 = s1[x1];
            const float top = v00 + wx * (v01 - v00);
            const float bot = v10 + wx * (v11 - v10);
            const float v   = top + wy * (bot - top);
            const float sg  = __fdividef(1.0f, 1.0f + __expf(-v));
            aI += sg * tv[p];
            aS += sg * sg;
            aT += tv[p];
        }
    }

#pragma unroll
    for (int off = 32; off > 0; off >>= 1) {
        aI += __shfl_down(aI, off, 64);
        aS += __shfl_down(aS, off, 64);
        aT += __shfl_down(aT, off, 64);
    }
    const int wv = tid >> 6;
    if ((tid & 63) == 0) {
        sred[wv * 3 + 0] = aI;
        sred[wv * 3 + 1] = aS;
        sred[wv * 3 + 2] = aT;
    }
    __syncthreads();
    if (tid == 0) {
        float* pt = part + (size_t)(n * NTILES + tile) * 3;
        pt[0] = sred[0] + sred[3] + sred[6] + sred[9];
        pt[1] = sred[1] + sred[4] + sred[7] + sred[10];
        pt[2] = sred[2] + sred[5] + sred[8] + sred[11];
    }
}

__global__ __launch_bounds__(256) void dmh_fin2(const float* __restrict__ part,
                                                float* __restrict__ out)
{
    const int i = blockIdx.x * 256 + threadIdx.x;
    if (i < NINST) {
        float I = 0.0f, S = 0.0f, T = 0.0f;
#pragma unroll
        for (int t = 0; t < NTILES; t++) {
            const float* pt = part + (size_t)(i * NTILES + t) * 3;
            I += pt[0]; S += pt[1]; T += pt[2];
        }
        out[i] = 1.0f - 2.0f * I / (S + T + 1e-5f);
    }
}

extern "C" void kernel_launch(void* const* d_in, const int* in_sizes, int n_in,
                              void* d_out, int out_size, void* d_ws, size_t ws_size,
                              hipStream_t stream) {
    const float* feats  = (const float*)d_in[0];
    const float* pars   = (const float*)d_in[1];
    const float* iloc   = (const float*)d_in[2];
    const float* gt     = (const float*)d_in[3];
    const int*   iminds = (const int*)d_in[4];
    const int*   lvls   = (const int*)d_in[5];

    float* part = (float*)d_ws;          // 512*8*3 floats = 48 KB
    dim3 grid(NTILES, NINST);
    dmh_fused3<<<grid, 256, 0, stream>>>(feats, pars, iloc, gt, iminds, lvls, part);
    dmh_fin2<<<(NINST + 255) / 256, 256, 0, stream>>>(part, (float*)d_out);
}